// Round 4
// baseline (3708.266 us; speedup 1.0000x reference)
//
#include <hip/hip_runtime.h>
#include <hip/hip_bf16.h>
#include <stdint.h>

typedef __attribute__((ext_vector_type(8))) short short8;
typedef __attribute__((ext_vector_type(4))) float floatx4;

#define B_ 64
#define T_ 256
#define H_ 1024
#define LATENT_ 256
#define P_ 128
#define BH_ (B_ * H_)
#define MFMA_(a, b, c) __builtin_amdgcn_mfma_f32_16x16x32_bf16(a, b, c, 0, 0, 0)
// LDS column swizzle for pbuf. Multiplier 4 (R11 post-mortem: 5 regressed
// conflicts 5.1e7->8.5e7 by breaking the MFMA-phase write aliasing, which is
// exactly 2-way (free) with 4*row).
#define PBI(n, row) (((n) + 4 * (row)) & 31)

// Dynamic-LDS partition (bytes): pbuf 64K | Whh slice 64K | Wih0 slice 8K
#define PBUF_OFF 0
#define WHH_OFF  65536
#define WIH0_OFF 131072
#define LDS_TOTAL 139264

// Completion counters: cnt[layer][slot] on its own 64B line (16 u32 stride).
// Slot s = t+1 in [0,258). Write-once-incremented per slot -> no ABA, no
// generation wrap. cnt[l][0] preset to 128 (h0 seed).
#define CNT_STRIDE 16
#define CNT_SLOTS 258
#define CNT_L (CNT_SLOTS * CNT_STRIDE)        // u32 offset of layer-1 region
#define CNT_WORDS (2 * CNT_L)                 // 8256 u32 = 33 KB

// Block-major h layout: element offset of (b, j) = ((j>>3)*64 + b)*8 + (j&7).
// Producer block (8 cols) writes 1KB contiguous; consumer 16-lane short8
// A-loads are 256B coalesced.

__device__ __forceinline__ float sigmoidf_(float x) {
    return 1.0f / (1.0f + __expf(-x));
}
__device__ __forceinline__ float tanh_fast(float x) {
    float e = __expf(2.0f * x);
    return 1.0f - 2.0f / (e + 1.0f);
}

// ---------------------------------------------------------------------------
__global__ __launch_bounds__(256) void cvt_f2b(
    const float* __restrict__ src, __hip_bfloat16* __restrict__ dst, int n)
{
    int i = (blockIdx.x * 256 + threadIdx.x) * 4;
    if (i < n) {
        float4 v = *(const float4*)(src + i);
        dst[i + 0] = __float2bfloat16(v.x);
        dst[i + 1] = __float2bfloat16(v.y);
        dst[i + 2] = __float2bfloat16(v.z);
        dst[i + 3] = __float2bfloat16(v.w);
    }
}

// h0 = z @ fc_init_w^T + fc_init_b -> the two t=-1 slots (block-major);
// init completion counters (slot 0 preset to 128).
__global__ __launch_bounds__(256) void h0_kernel(
    const float* __restrict__ z,
    const float* __restrict__ fw,
    const float* __restrict__ fb,
    __hip_bfloat16* __restrict__ h1dst,
    __hip_bfloat16* __restrict__ h2dst,
    unsigned* __restrict__ cnt)
{
    int idx = blockIdx.x * 256 + threadIdx.x;      // 0..65535
    if (idx < CNT_WORDS)
        cnt[idx] = ((idx % CNT_L) == 0) ? 128u : 0u;   // [l][0][word0] = 128
    int b = idx >> 10, j = idx & 1023;
    const float* zp = z + b * LATENT_;
    const float* wp = fw + j * LATENT_;
    float acc = fb[j];
    for (int k = 0; k < LATENT_; k += 4) {
        float4 zv = *(const float4*)(zp + k);
        float4 wv = *(const float4*)(wp + k);
        acc += zv.x * wv.x + zv.y * wv.y + zv.z * wv.z + zv.w * wv.w;
    }
    __hip_bfloat16 hb = __float2bfloat16(acc);
    int off = ((j >> 3) * 64 + b) * 8 + (j & 7);   // block-major
    h1dst[off] = hb;
    h2dst[off] = hb;
}

struct PParams {
    const __hip_bfloat16 *tseqb, *stokb;
    const __hip_bfloat16 *Wih0b, *Whh0b, *Wih1b, *Whh1b, *owb;
    const float *bih0, *bhh0, *bih1, *bhh1, *ob;
    __hip_bfloat16 *h1seq;    // T+1 slots, write-once per t (slot t+1)
    __hip_bfloat16 *h2seq;    // T+1 slots
    float* out;               // (B, T, P)
    unsigned* cnt;            // completion counters (see CNT_* macros)
};

// ---------------------------------------------------------------------------
// Persistent dataflow LSTM. 256 blocks x 512 threads (8 waves), 1 block/CU.
//   blocks   0..127 : layer-1 step t=phase-1 (8 cols x 4 gates, N=32 rows)
//   blocks 128..255 : layer-0 step t=phase
// R12: NO device barrier. R8/R9/R11 showed all barrier shapes land at
// 3.1-4.1ms -> the protocol hops (arrive->leader->release->detect) and the
// cross-group max-skew are the cost, not the traffic shape. Replaced by
// per-slot completion counters polled directly by consumers:
//   L0 @ p waits cnt1[p]==128            (h1(p-1) full)
//   L1 @ p waits cnt1[p] && cnt2[p-1]    (h1(p-1), h2(p-2) full)
// Producer: h-store (agent, write-through) -> __syncthreads (vmcnt drain at
// LLC) -> tid0 fetch_add(cnt[layer][t+1]). Monotone write-once slots ->
// deadlock-free by induction from preset slot 0.
// ---------------------------------------------------------------------------
__global__ __launch_bounds__(512, 2) void lstm_persistent(PParams p)
{
    extern __shared__ char dynlds[];
    float (*pbuf)[64][32] = (float (*)[64][32])(dynlds + PBUF_OFF);
    short8* whh8 = (short8*)(dynlds + WHH_OFF);   // [r*128 + (kc ^ (r&7))]
    short8* wx8  = (short8*)(dynlds + WIH0_OFF);  // [r*16  + (kc ^ (r&7))]

    const int tid  = threadIdx.x;
    const int bid  = blockIdx.x;
    const int wv   = tid >> 6;
    const int l    = tid & 63;
    const int l15  = l & 15;
    const int quad = l >> 4;
    const int ks   = quad * 8;
    const bool isL1 = bid < 128;
    const int colbase = (isL1 ? bid : bid - 128) * 8;
    const int hblk = colbase >> 3;     // own column-block index (0..127)
    // B-frag rows: nt=0 -> gates {i,f} (local rows 0..15), nt=1 -> {g,o} (+16)
    const int r0l  = (l15 >> 3) * 8 + (l15 & 7);       // local row, gates 0/1
    const int row0 = ((l15 >> 3)    ) * H_ + colbase + (l15 & 7);  // global
    const int row1 = ((l15 >> 3) + 2) * H_ + colbase + (l15 & 7);

    auto h1slot = [&](int t) { return p.h1seq + (size_t)(t + 1) * BH_; };
    auto h2slot = [&](int t) { return p.h2seq + (size_t)(t + 1) * BH_; };

    // ---- stage recurrent weights into LDS (once) ----
    {
        const short* Wh = (const short*)(isL1 ? p.Whh1b : p.Whh0b);
        for (int i = tid; i < 32 * 128; i += 512) {
            int r = i >> 7, kc = i & 127;
            int grow = (r >> 3) * H_ + colbase + (r & 7);
            whh8[r * 128 + (kc ^ (r & 7))] =
                *(const short8*)(Wh + (size_t)grow * H_ + kc * 8);
        }
        if (!isL1) {
            const short* Wx = (const short*)p.Wih0b;
            for (int i = tid; i < 32 * 16; i += 512) {
                int r = i >> 4, kc = i & 15;
                int grow = (r >> 3) * H_ + colbase + (r & 7);
                wx8[r * 16 + (kc ^ (r & 7))] =
                    *(const short8*)(Wx + (size_t)grow * P_ + kc * 8);
            }
        }
    }
    __syncthreads();

    // Cell duty: ALL 512 threads, one cell each (b = tid>>3, col = tid&7).
    const int cm  = tid >> 3;          // batch row
    const int c0  = tid & 7;           // column within block slice
    const int cj0 = colbase + c0;
    const float* bi = isL1 ? p.bih1 : p.bih0;
    const float* bh = isL1 ? p.bhh1 : p.bhh0;
    float bs[4];                       // {i,f,g,o} for this cell
#pragma unroll
    for (int g = 0; g < 4; ++g)
        bs[g] = bi[g * H_ + cj0] + bh[g * H_ + cj0];
    float creg = 0.0f;

    for (int phase = 0; phase <= T_; ++phase) {
        const bool doGemm = isL1 ? (phase >= 1) : (phase < T_);
        const int t = isL1 ? phase - 1 : phase;
        if (!doGemm) continue;

        // ---- dataflow wait: h1 slot 'phase'; L1 also h2 slot 'phase-1' ----
        if (tid == 0) {
            const unsigned* c1 = p.cnt + (size_t)phase * CNT_STRIDE;
            const unsigned* c2 = p.cnt + CNT_L + (size_t)(phase - 1) * CNT_STRIDE;
            for (;;) {
                unsigned a = __hip_atomic_load(c1, __ATOMIC_RELAXED,
                                               __HIP_MEMORY_SCOPE_AGENT);
                unsigned b2 = 128u;
                if (isL1) b2 = __hip_atomic_load(c2, __ATOMIC_RELAXED,
                                                 __HIP_MEMORY_SCOPE_AGENT);
                if (a >= 128u && b2 >= 128u) break;
                __builtin_amdgcn_s_sleep(4);
            }
        }
        asm volatile("" ::: "memory");   // no hoisting above the spin
        __syncthreads();

        floatx4 acc[8] = {};
        if (isL1) {
            // gates1 = [h1(t) | h2(t-1)] @ [Wih1 | Whh1]^T, K=2048.
            if (wv < 4) {
                // Wih1 half from L2 (resident: 1 MB/XCD footprint)
                const short* A  = (const short*)h1slot(t);
                const short* w0 = (const short*)p.Wih1b + (long)row0 * H_ + wv * 256 + ks;
                const short* w1 = (const short*)p.Wih1b + (long)row1 * H_ + wv * 256 + ks;
                short8 af[32];
#pragma unroll
                for (int c = 0; c < 8; ++c)
#pragma unroll
                    for (int mt = 0; mt < 4; ++mt)
                        af[c * 4 + mt] = *(const short8*)(A +
                            ((long)((wv * 32 + c * 4 + quad) * 64 + mt * 16 + l15) << 3));
#pragma unroll
                for (int c = 0; c < 8; ++c) {
                    short8 b0 = *(const short8*)(w0 + c * 32);
                    short8 b1 = *(const short8*)(w1 + c * 32);
#pragma unroll
                    for (int mt = 0; mt < 4; ++mt) {
                        acc[2 * mt]     = MFMA_(af[c * 4 + mt], b0, acc[2 * mt]);
                        acc[2 * mt + 1] = MFMA_(af[c * 4 + mt], b1, acc[2 * mt + 1]);
                    }
                }
            } else {
                // Whh1 half from LDS
                const short* A = (const short*)h2slot(t - 1);
                short8 af[32];
#pragma unroll
                for (int c = 0; c < 8; ++c)
#pragma unroll
                    for (int mt = 0; mt < 4; ++mt)
                        af[c * 4 + mt] = *(const short8*)(A +
                            ((long)(((wv - 4) * 32 + c * 4 + quad) * 64 + mt * 16 + l15) << 3));
#pragma unroll
                for (int c = 0; c < 8; ++c) {
                    int kcq = (wv - 4) * 32 + quad + c * 4;
                    short8 b0 = whh8[r0l * 128 + (kcq ^ (r0l & 7))];
                    short8 b1 = whh8[(r0l + 16) * 128 + (kcq ^ (r0l & 7))];
#pragma unroll
                    for (int mt = 0; mt < 4; ++mt) {
                        acc[2 * mt]     = MFMA_(af[c * 4 + mt], b0, acc[2 * mt]);
                        acc[2 * mt + 1] = MFMA_(af[c * 4 + mt], b1, acc[2 * mt + 1]);
                    }
                }
            }
        } else {
            // gates0 = [x_t | h1(t-1)] @ [Wih0 | Whh0]^T, K=128+1024.
            const short* Ah = (const short*)h1slot(t - 1);
            const short* Ax; long xstr;
            if (t == 0) { Ax = (const short*)p.stokb; xstr = 0; }
            else { Ax = (const short*)p.tseqb + (long)(t - 1) * P_; xstr = (long)T_ * P_; }
            short8 af[16];
#pragma unroll
            for (int c = 0; c < 4; ++c)
#pragma unroll
                for (int mt = 0; mt < 4; ++mt)
                    af[c * 4 + mt] = *(const short8*)(Ah +
                        ((long)((wv * 16 + c * 4 + quad) * 64 + mt * 16 + l15) << 3));
            short8 xf[4];
            if (wv < 4) {
#pragma unroll
                for (int mt = 0; mt < 4; ++mt)
                    xf[mt] = *(const short8*)(Ax + (long)(mt * 16 + l15) * xstr + wv * 32 + ks);
            }
#pragma unroll
            for (int c = 0; c < 4; ++c) {
                int kcq = wv * 16 + quad + c * 4;
                short8 b0 = whh8[r0l * 128 + (kcq ^ (r0l & 7))];
                short8 b1 = whh8[(r0l + 16) * 128 + (kcq ^ (r0l & 7))];
#pragma unroll
                for (int mt = 0; mt < 4; ++mt) {
                    acc[2 * mt]     = MFMA_(af[c * 4 + mt], b0, acc[2 * mt]);
                    acc[2 * mt + 1] = MFMA_(af[c * 4 + mt], b1, acc[2 * mt + 1]);
                }
            }
            if (wv < 4) {   // x-part chunk wv (Wih0 from LDS)
                int kcx = wv * 4 + quad;
                short8 b0 = wx8[r0l * 16 + (kcx ^ (r0l & 7))];
                short8 b1 = wx8[(r0l + 16) * 16 + (kcx ^ (r0l & 7))];
#pragma unroll
                for (int mt = 0; mt < 4; ++mt) {
                    acc[2 * mt]     = MFMA_(xf[mt], b0, acc[2 * mt]);
                    acc[2 * mt + 1] = MFMA_(xf[mt], b1, acc[2 * mt + 1]);
                }
            }
        }
        // C/D: col = lane&15, row = quad*4 + reg (+ mt*16)
#pragma unroll
        for (int mt = 0; mt < 4; ++mt)
#pragma unroll
            for (int nt = 0; nt < 2; ++nt)
#pragma unroll
                for (int r = 0; r < 4; ++r) {
                    int row = mt * 16 + quad * 4 + r;
                    pbuf[wv][row][PBI(nt * 16 + l15, row)] = acc[2 * mt + nt][r];
                }
        __syncthreads();

        // ---- cell: all 512 threads, one column each ----
        {
            // gate n-layout: i: [0,8) f: [8,16) g: [16,24) o: [24,32)
            float v[4];
#pragma unroll
            for (int g = 0; g < 4; ++g) v[g] = bs[g];
#pragma unroll
            for (int w2 = 0; w2 < 8; ++w2)
#pragma unroll
                for (int g = 0; g < 4; ++g)
                    v[g] += pbuf[w2][cm][PBI(8 * g + c0, cm)];
            float cn = sigmoidf_(v[1]) * creg + sigmoidf_(v[0]) * tanh_fast(v[2]);
            float hv = sigmoidf_(v[3]) * tanh_fast(cn);
            creg = cn;
            __hip_bfloat16* hdst = isL1 ? h2slot(t) : h1slot(t);
            __hip_bfloat16 hb = __float2bfloat16(hv);
            unsigned short hu = *(unsigned short*)&hb;
            // Block-major: block writes u16[hblk*512 + tid] -> 1KB contiguous.
            // Agent-scope write-through: LLC holds the truth for consumers.
            __hip_atomic_store((unsigned short*)hdst + hblk * 512 + tid, hu,
                               __ATOMIC_RELAXED, __HIP_MEMORY_SCOPE_AGENT);
        }

        // __syncthreads drains each wave's vmcnt(0): h stores complete at LLC
        __syncthreads();
        if (tid == 0)
            __hip_atomic_fetch_add(p.cnt + (isL1 ? CNT_L : 0)
                                         + (size_t)(t + 1) * CNT_STRIDE,
                                   1u, __ATOMIC_RELAXED, __HIP_MEMORY_SCOPE_AGENT);
    }

    // ---- Post-loop output projection: one block per timestep t = bid ----
    // out[:, t, :] = sigmoid(h2(t) @ ow^T + ob); M=64, N=128, K=1024.
    // Wave (nh = wv>>1, kh = wv&1): N=32 (2 B-frags), K=512.
    {
        const int t = bid;
        // wait for h2(t) complete (cnt2[t+1] == 128)
        if (tid == 0) {
            const unsigned* c2 = p.cnt + CNT_L + (size_t)(t + 1) * CNT_STRIDE;
            while (__hip_atomic_load(c2, __ATOMIC_RELAXED,
                                     __HIP_MEMORY_SCOPE_AGENT) < 128u)
                __builtin_amdgcn_s_sleep(4);
        }
        asm volatile("" ::: "memory");
        __syncthreads();

        const int nh = wv >> 1, kh = wv & 1;
        const short* A  = (const short*)h2slot(t);
        const short* Wb = (const short*)p.owb;
        floatx4 oacc[8] = {};
        for (int c = 0; c < 16; ++c) {
            int kk = kh * 512 + c * 32 + ks;
            short8 b0 = *(const short8*)(Wb + (long)(nh * 32 + l15) * H_ + kk);
            short8 b1 = *(const short8*)(Wb + (long)(nh * 32 + 16 + l15) * H_ + kk);
#pragma unroll
            for (int mt = 0; mt < 4; ++mt) {
                short8 a = *(const short8*)(A +
                    ((long)((kh * 64 + c * 4 + quad) * 64 + mt * 16 + l15) << 3));
                oacc[2 * mt]     = MFMA_(a, b0, oacc[2 * mt]);
                oacc[2 * mt + 1] = MFMA_(a, b1, oacc[2 * mt + 1]);
            }
        }
#pragma unroll
        for (int mt = 0; mt < 4; ++mt)
#pragma unroll
            for (int nt = 0; nt < 2; ++nt)
#pragma unroll
                for (int r = 0; r < 4; ++r) {
                    int row = mt * 16 + quad * 4 + r;
                    pbuf[wv][row][PBI(nt * 16 + l15, row)] = oacc[2 * mt + nt][r];
                }
        __syncthreads();
        for (int i = tid; i < 64 * 128; i += 512) {
            int m = i >> 7, pp2 = i & 127;
            int nh2 = pp2 >> 5, pc = pp2 & 31;
            float v = pbuf[2 * nh2][m][PBI(pc, m)] + pbuf[2 * nh2 + 1][m][PBI(pc, m)]
                    + p.ob[pp2];
            p.out[(long)m * (T_ * P_) + (long)t * P_ + pp2] = sigmoidf_(v);
        }
    }
}

// ---------------------------------------------------------------------------
extern "C" void kernel_launch(void* const* d_in, const int* in_sizes, int n_in,
                              void* d_out, int out_size, void* d_ws, size_t ws_size,
                              hipStream_t stream) {
    const float* z    = (const float*)d_in[0];
    const float* tseq = (const float*)d_in[1];
    const float* fw   = (const float*)d_in[2];
    const float* fb   = (const float*)d_in[3];
    const float* stok = (const float*)d_in[4];
    const float* Wih0 = (const float*)d_in[5];
    const float* Whh0 = (const float*)d_in[6];
    const float* bih0 = (const float*)d_in[7];
    const float* bhh0 = (const float*)d_in[8];
    const float* Wih1 = (const float*)d_in[9];
    const float* Whh1 = (const float*)d_in[10];
    const float* bih1 = (const float*)d_in[11];
    const float* bhh1 = (const float*)d_in[12];
    const float* ow   = (const float*)d_in[13];
    const float* ob   = (const float*)d_in[14];
    float* out = (float*)d_out;

    // Workspace (~93.3 MB).
    const size_t FULLH = (size_t)(T_ + 1) * BH_ * 2;
    char* ws = (char*)d_ws;
    size_t off = 0;
    __hip_bfloat16* Wih0b = (__hip_bfloat16*)(ws + off); off += (size_t)4 * H_ * P_ * 2;
    __hip_bfloat16* Whh0b = (__hip_bfloat16*)(ws + off); off += (size_t)4 * H_ * H_ * 2;
    __hip_bfloat16* Wih1b = (__hip_bfloat16*)(ws + off); off += (size_t)4 * H_ * H_ * 2;
    __hip_bfloat16* Whh1b = (__hip_bfloat16*)(ws + off); off += (size_t)4 * H_ * H_ * 2;
    __hip_bfloat16* owb   = (__hip_bfloat16*)(ws + off); off += (size_t)P_ * H_ * 2;
    __hip_bfloat16* tseqb = (__hip_bfloat16*)(ws + off); off += (size_t)B_ * T_ * P_ * 2;
    __hip_bfloat16* stokb = (__hip_bfloat16*)(ws + off); off += 256;
    __hip_bfloat16* h1seq = (__hip_bfloat16*)(ws + off); off += FULLH;
    __hip_bfloat16* h2seq = (__hip_bfloat16*)(ws + off); off += FULLH;
    unsigned* cnt         = (unsigned*)(ws + off);       off += (size_t)CNT_WORDS * 4;

    auto cvt = [&](const float* s, __hip_bfloat16* d, int n) {
        hipLaunchKernelGGL(cvt_f2b, dim3((n / 4 + 255) / 256), dim3(256), 0, stream, s, d, n);
    };
    cvt(Wih0, Wih0b, 4 * H_ * P_);
    cvt(Whh0, Whh0b, 4 * H_ * H_);
    cvt(Wih1, Wih1b, 4 * H_ * H_);
    cvt(Whh1, Whh1b, 4 * H_ * H_);
    cvt(ow,   owb,   P_ * H_);
    cvt(tseq, tseqb, B_ * T_ * P_);
    cvt(stok, stokb, P_);

    // h0 into the t=-1 slots (slot 0 of each sequence); init counters.
    hipLaunchKernelGGL(h0_kernel, dim3(256), dim3(256), 0, stream,
                       z, fw, fb, h1seq, h2seq, cnt);

    PParams pp;
    pp.tseqb = tseqb; pp.stokb = stokb;
    pp.Wih0b = Wih0b; pp.Whh0b = Whh0b; pp.Wih1b = Wih1b; pp.Whh1b = Whh1b;
    pp.owb = owb;
    pp.bih0 = bih0; pp.bhh0 = bhh0; pp.bih1 = bih1; pp.bhh1 = bhh1; pp.ob = ob;
    pp.h1seq = h1seq; pp.h2seq = h2seq;
    pp.out = out;
    pp.cnt = cnt;

    // 136 KB dynamic LDS (<= 160 KiB/CU on gfx950); must raise the cap first.
    hipFuncSetAttribute((const void*)lstm_persistent,
                        hipFuncAttributeMaxDynamicSharedMemorySize, LDS_TOTAL);
    void* args[] = { &pp };
    hipLaunchCooperativeKernel((void*)lstm_persistent, dim3(256), dim3(512),
                               args, LDS_TOTAL, stream);
}

// Round 5
// 1921.779 us; speedup vs baseline: 1.9296x; 1.9296x over previous
//
#include <hip/hip_runtime.h>
#include <hip/hip_bf16.h>
#include <stdint.h>

typedef __attribute__((ext_vector_type(8))) short short8;
typedef __attribute__((ext_vector_type(4))) float floatx4;

#define B_ 64
#define T_ 256
#define H_ 1024
#define LATENT_ 256
#define P_ 128
#define BH_ (B_ * H_)
#define MFMA_(a, b, c) __builtin_amdgcn_mfma_f32_16x16x32_bf16(a, b, c, 0, 0, 0)
// LDS column swizzle for pbuf (multiplier 4: MFMA-phase writes alias exactly
// 2-way = free; 5 regressed conflicts 5.1e7->8.5e7 in R11).
#define PBI(n, row) (((n) + 4 * (row)) & 31)

// Dynamic-LDS partition (bytes): pbuf 64K | Whh slice 64K | Wih0 slice 8K
#define PBUF_OFF 0
#define WHH_OFF  65536
#define WIH0_OFF 131072
#define LDS_TOTAL 139264

// ---- Sync v5 (R13) ----
// arrive: fetch_add, fan-in 8 (16 lines per layer-group per slot).
// leader (bid128 for L0-group, bid0 for L1-group) aggregates 16 words,
// publishes ready flag replicated on 8 lines (one per consumer wave id).
// consumers: single-lane (lane0-of-wave) polls its replica. All spin loads
// single-lane: R9/R12 showed reader-count x line-count is the spin cost.
#define SLOTS 258
#define CIDX(lay, slot) (((size_t)(lay) * SLOTS + (slot)) * 256)   // +line*16
#define RIDX(lay, slot) (((size_t)(lay) * SLOTS + (slot)) * 128)   // +wv*16
#define CNTW (2 * SLOTS * 256)
#define RDYW (2 * SLOTS * 128)

// Block-major h layout: element offset of (b, j) = ((j>>3)*64 + b)*8 + (j&7).
// Producer block writes 1KB contiguous; consumer short8 A-loads 256B coalesced.

__device__ __forceinline__ float sigmoidf_(float x) {
    return 1.0f / (1.0f + __expf(-x));
}
__device__ __forceinline__ float tanh_fast(float x) {
    float e = __expf(2.0f * x);
    return 1.0f - 2.0f / (e + 1.0f);
}

// ---------------------------------------------------------------------------
__global__ __launch_bounds__(256) void cvt_f2b(
    const float* __restrict__ src, __hip_bfloat16* __restrict__ dst, int n)
{
    int i = (blockIdx.x * 256 + threadIdx.x) * 4;
    if (i < n) {
        float4 v = *(const float4*)(src + i);
        dst[i + 0] = __float2bfloat16(v.x);
        dst[i + 1] = __float2bfloat16(v.y);
        dst[i + 2] = __float2bfloat16(v.z);
        dst[i + 3] = __float2bfloat16(v.w);
    }
}

// h0 -> the two t=-1 slots (block-major); init cnt (0) and rdy (slot0 = 1).
__global__ __launch_bounds__(256) void h0_kernel(
    const float* __restrict__ z,
    const float* __restrict__ fw,
    const float* __restrict__ fb,
    __hip_bfloat16* __restrict__ h1dst,
    __hip_bfloat16* __restrict__ h2dst,
    unsigned* __restrict__ cnt,
    unsigned* __restrict__ rdy)
{
    int idx = blockIdx.x * 256 + threadIdx.x;      // 0..65535
    for (int i = idx; i < CNTW; i += 65536) cnt[i] = 0u;
    for (int i = idx; i < RDYW; i += 65536) {
        int slot = (i >> 7) % SLOTS;
        rdy[i] = (slot == 0) ? 1u : 0u;
    }
    int b = idx >> 10, j = idx & 1023;
    const float* zp = z + b * LATENT_;
    const float* wp = fw + j * LATENT_;
    float acc = fb[j];
    for (int k = 0; k < LATENT_; k += 4) {
        float4 zv = *(const float4*)(zp + k);
        float4 wv = *(const float4*)(wp + k);
        acc += zv.x * wv.x + zv.y * wv.y + zv.z * wv.z + zv.w * wv.w;
    }
    __hip_bfloat16 hb = __float2bfloat16(acc);
    int off = ((j >> 3) * 64 + b) * 8 + (j & 7);   // block-major
    h1dst[off] = hb;
    h2dst[off] = hb;
}

struct PParams {
    const __hip_bfloat16 *tseqb, *stokb;
    const __hip_bfloat16 *Wih0b, *Whh0b, *Wih1b, *Whh1b, *owb;
    const float *bih0, *bhh0, *bih1, *bhh1, *ob;
    __hip_bfloat16 *h1seq;    // T+1 slots, write-once per t (slot t+1)
    __hip_bfloat16 *h2seq;    // T+1 slots
    float* out;               // (B, T, P)
    unsigned* cnt;            // arrival counters (CIDX)
    unsigned* rdy;            // replicated ready flags (RIDX)
};

// ---------------------------------------------------------------------------
// Persistent dataflow LSTM. 256 blocks x 512 threads (8 waves), 1 block/CU.
//   blocks   0..127 : layer-1 step t=phase-1 ; blocks 128..255 : layer-0 t=phase
// R13: phase time is dominated by latency-bound A-streaming (~4KB/CU in
// flight vs 200-600cy LLC/L2 latency -> ~2.6us per 128KB when 8 waves load,
// 2x worse when only 4 do). So: (a) split-K L1 - every wave takes 128 of h2
// (dep: own group, ready early) AND 128 of h1; h2 loads issue BEFORE the h1
// wait, h1 wait overlaps their latency, all 8 waves stream h1 after.
// (b) per-wave single-lane waits, no pre-GEMM __syncthreads.
// (c) sync v5: 8-deep RMW fan-in, per-group leader, 8x-replicated flag.
// ---------------------------------------------------------------------------
__global__ __launch_bounds__(512, 2) void lstm_persistent(PParams p)
{
    extern __shared__ char dynlds[];
    float (*pbuf)[64][32] = (float (*)[64][32])(dynlds + PBUF_OFF);
    short8* whh8 = (short8*)(dynlds + WHH_OFF);   // [r*128 + (kc ^ (r&7))]
    short8* wx8  = (short8*)(dynlds + WIH0_OFF);  // [r*16  + (kc ^ (r&7))]

    const int tid  = threadIdx.x;
    const int bid  = blockIdx.x;
    const int wv   = tid >> 6;
    const int l    = tid & 63;
    const int l15  = l & 15;
    const int quad = l >> 4;
    const int ks   = quad * 8;
    const bool isL1 = bid < 128;
    const int colbase = (isL1 ? bid : bid - 128) * 8;
    const int hblk = colbase >> 3;     // own column-block index (0..127)
    const int r0l  = (l15 >> 3) * 8 + (l15 & 7);       // local row, gates 0/1
    const int row0 = ((l15 >> 3)    ) * H_ + colbase + (l15 & 7);
    const int row1 = ((l15 >> 3) + 2) * H_ + colbase + (l15 & 7);

    auto h1slot = [&](int t) { return p.h1seq + (size_t)(t + 1) * BH_; };
    auto h2slot = [&](int t) { return p.h2seq + (size_t)(t + 1) * BH_; };

    // lane0-of-wave spin on the wave's flag replica (single-lane poll).
    auto wspin = [&](int lay, int slot) {
        if (l == 0) {
            const unsigned* rf = p.rdy + RIDX(lay, slot) + wv * 16;
            while (__hip_atomic_load(rf, __ATOMIC_RELAXED,
                                     __HIP_MEMORY_SCOPE_AGENT) == 0u)
                __builtin_amdgcn_s_sleep(2);
        }
        asm volatile("" ::: "memory");
    };

    // ---- stage recurrent weights into LDS (once) ----
    {
        const short* Wh = (const short*)(isL1 ? p.Whh1b : p.Whh0b);
        for (int i = tid; i < 32 * 128; i += 512) {
            int r = i >> 7, kc = i & 127;
            int grow = (r >> 3) * H_ + colbase + (r & 7);
            whh8[r * 128 + (kc ^ (r & 7))] =
                *(const short8*)(Wh + (size_t)grow * H_ + kc * 8);
        }
        if (!isL1) {
            const short* Wx = (const short*)p.Wih0b;
            for (int i = tid; i < 32 * 16; i += 512) {
                int r = i >> 4, kc = i & 15;
                int grow = (r >> 3) * H_ + colbase + (r & 7);
                wx8[r * 16 + (kc ^ (r & 7))] =
                    *(const short8*)(Wx + (size_t)grow * P_ + kc * 8);
            }
        }
    }
    __syncthreads();

    // Cell duty: all 512 threads, one cell each (b = tid>>3, col = tid&7).
    const int cm  = tid >> 3;
    const int c0  = tid & 7;
    const int cj0 = colbase + c0;
    const float* bi = isL1 ? p.bih1 : p.bih0;
    const float* bh = isL1 ? p.bhh1 : p.bhh0;
    float bs[4];
#pragma unroll
    for (int g = 0; g < 4; ++g)
        bs[g] = bi[g * H_ + cj0] + bh[g * H_ + cj0];
    float creg = 0.0f;

    const int lay = isL1 ? 1 : 0;

    for (int phase = 0; phase <= T_; ++phase) {
        const bool doGemm = isL1 ? (phase >= 1) : (phase < T_);
        const int t = isL1 ? phase - 1 : phase;
        if (!doGemm) continue;

        floatx4 acc[8] = {};
        if (isL1) {
            // ---- h2 half (dep: own group slot phase-1, ready early) ----
            wspin(1, phase - 1);
            const short* A2 = (const short*)h2slot(t - 1);
            short8 af2[16];
#pragma unroll
            for (int c = 0; c < 4; ++c)
#pragma unroll
                for (int mt = 0; mt < 4; ++mt) {
                    int kR = wv * 16 + c * 4 + quad;
                    af2[c * 4 + mt] = *(const short8*)(A2 +
                        ((long)(kR * 64 + mt * 16 + l15) << 3));
                }
            // ---- h1 wait overlaps af2 in-flight latency ----
            wspin(0, phase);
            const short* A1 = (const short*)h1slot(t);
            short8 af1[16];
#pragma unroll
            for (int c = 0; c < 4; ++c)
#pragma unroll
                for (int mt = 0; mt < 4; ++mt) {
                    int kR = wv * 16 + c * 4 + quad;
                    af1[c * 4 + mt] = *(const short8*)(A1 +
                        ((long)(kR * 64 + mt * 16 + l15) << 3));
                }
            // h2 x Whh1 (LDS)
#pragma unroll
            for (int c = 0; c < 4; ++c) {
                int kR = wv * 16 + c * 4 + quad;
                short8 b0 = whh8[r0l * 128 + (kR ^ (r0l & 7))];
                short8 b1 = whh8[(r0l + 16) * 128 + (kR ^ (r0l & 7))];
#pragma unroll
                for (int mt = 0; mt < 4; ++mt) {
                    acc[2 * mt]     = MFMA_(af2[c * 4 + mt], b0, acc[2 * mt]);
                    acc[2 * mt + 1] = MFMA_(af2[c * 4 + mt], b1, acc[2 * mt + 1]);
                }
            }
            // h1 x Wih1 (global, L2-resident)
            const short* w0 = (const short*)p.Wih1b + (long)row0 * H_;
            const short* w1 = (const short*)p.Wih1b + (long)row1 * H_;
#pragma unroll
            for (int c = 0; c < 4; ++c) {
                int kR = wv * 16 + c * 4 + quad;
                short8 b0 = *(const short8*)(w0 + kR * 8);
                short8 b1 = *(const short8*)(w1 + kR * 8);
#pragma unroll
                for (int mt = 0; mt < 4; ++mt) {
                    acc[2 * mt]     = MFMA_(af1[c * 4 + mt], b0, acc[2 * mt]);
                    acc[2 * mt + 1] = MFMA_(af1[c * 4 + mt], b1, acc[2 * mt + 1]);
                }
            }
        } else {
            // ---- x prefetch before the wait (no dependency) ----
            const short* Ax; long xstr;
            if (t == 0) { Ax = (const short*)p.stokb; xstr = 0; }
            else { Ax = (const short*)p.tseqb + (long)(t - 1) * P_; xstr = (long)T_ * P_; }
            short8 xf[4];
            if (wv < 4) {
#pragma unroll
                for (int mt = 0; mt < 4; ++mt)
                    xf[mt] = *(const short8*)(Ax + (long)(mt * 16 + l15) * xstr + wv * 32 + ks);
            }
            wspin(0, phase);
            const short* Ah = (const short*)h1slot(t - 1);
            short8 af[16];
#pragma unroll
            for (int c = 0; c < 4; ++c)
#pragma unroll
                for (int mt = 0; mt < 4; ++mt) {
                    int kR = wv * 16 + c * 4 + quad;
                    af[c * 4 + mt] = *(const short8*)(Ah +
                        ((long)(kR * 64 + mt * 16 + l15) << 3));
                }
            if (wv < 4) {   // x-part chunk wv (Wih0 from LDS) - xf arrived
                int kcx = wv * 4 + quad;
                short8 b0 = wx8[r0l * 16 + (kcx ^ (r0l & 7))];
                short8 b1 = wx8[(r0l + 16) * 16 + (kcx ^ (r0l & 7))];
#pragma unroll
                for (int mt = 0; mt < 4; ++mt) {
                    acc[2 * mt]     = MFMA_(xf[mt], b0, acc[2 * mt]);
                    acc[2 * mt + 1] = MFMA_(xf[mt], b1, acc[2 * mt + 1]);
                }
            }
#pragma unroll
            for (int c = 0; c < 4; ++c) {
                int kR = wv * 16 + c * 4 + quad;
                short8 b0 = whh8[r0l * 128 + (kR ^ (r0l & 7))];
                short8 b1 = whh8[(r0l + 16) * 128 + (kR ^ (r0l & 7))];
#pragma unroll
                for (int mt = 0; mt < 4; ++mt) {
                    acc[2 * mt]     = MFMA_(af[c * 4 + mt], b0, acc[2 * mt]);
                    acc[2 * mt + 1] = MFMA_(af[c * 4 + mt], b1, acc[2 * mt + 1]);
                }
            }
        }
        // C/D: col = lane&15, row = quad*4 + reg (+ mt*16)
#pragma unroll
        for (int mt = 0; mt < 4; ++mt)
#pragma unroll
            for (int nt = 0; nt < 2; ++nt)
#pragma unroll
                for (int r = 0; r < 4; ++r) {
                    int row = mt * 16 + quad * 4 + r;
                    pbuf[wv][row][PBI(nt * 16 + l15, row)] = acc[2 * mt + nt][r];
                }
        __syncthreads();

        // ---- cell: all 512 threads, one column each ----
        {
            float v[4];
#pragma unroll
            for (int g = 0; g < 4; ++g) v[g] = bs[g];
#pragma unroll
            for (int w2 = 0; w2 < 8; ++w2)
#pragma unroll
                for (int g = 0; g < 4; ++g)
                    v[g] += pbuf[w2][cm][PBI(8 * g + c0, cm)];
            float cn = sigmoidf_(v[1]) * creg + sigmoidf_(v[0]) * tanh_fast(v[2]);
            float hv = sigmoidf_(v[3]) * tanh_fast(cn);
            creg = cn;
            __hip_bfloat16* hdst = isL1 ? h2slot(t) : h1slot(t);
            __hip_bfloat16 hb = __float2bfloat16(hv);
            unsigned short hu = *(unsigned short*)&hb;
            __hip_atomic_store((unsigned short*)hdst + hblk * 512 + tid, hu,
                               __ATOMIC_RELAXED, __HIP_MEMORY_SCOPE_AGENT);
        }

        // __syncthreads drains each wave's vmcnt(0): h stores complete at LLC
        __syncthreads();
        if (tid == 0) {
            // arrive: fan-in 8 (16 lines per group-slot)
            __hip_atomic_fetch_add(p.cnt + CIDX(lay, t + 1) + (hblk >> 3) * 16,
                                   1u, __ATOMIC_RELAXED, __HIP_MEMORY_SCOPE_AGENT);
            if (bid == 128 || bid == 0) {
                // leader: aggregate own group, publish 8 flag replicas
                unsigned* cb = p.cnt + CIDX(lay, t + 1);
                for (;;) {
                    unsigned ok = 1;
#pragma unroll
                    for (int i2 = 0; i2 < 16; ++i2)
                        ok &= (__hip_atomic_load(cb + i2 * 16, __ATOMIC_RELAXED,
                                                 __HIP_MEMORY_SCOPE_AGENT) >= 8u);
                    if (ok) break;
                    __builtin_amdgcn_s_sleep(1);
                }
                asm volatile("" ::: "memory");
                unsigned* rb = p.rdy + RIDX(lay, t + 1);
#pragma unroll
                for (int w = 0; w < 8; ++w)
                    __hip_atomic_store(rb + w * 16, 1u,
                                       __ATOMIC_RELAXED, __HIP_MEMORY_SCOPE_AGENT);
            }
        }
        // NOTE: no trailing block barrier - next phase's per-wave spins gate.
        __syncthreads();   // pbuf reuse safety: cell reads done before overwrite
    }

    // ---- Post-loop output projection: one block per timestep t = bid ----
    {
        const int t = bid;
        wspin(1, t + 1);               // h2(t) complete
        __syncthreads();

        const int nh = wv >> 1, kh = wv & 1;
        const short* A  = (const short*)h2slot(t);
        const short* Wb = (const short*)p.owb;
        floatx4 oacc[8] = {};
        for (int c = 0; c < 16; ++c) {
            int kk = kh * 512 + c * 32 + ks;
            short8 b0 = *(const short8*)(Wb + (long)(nh * 32 + l15) * H_ + kk);
            short8 b1 = *(const short8*)(Wb + (long)(nh * 32 + 16 + l15) * H_ + kk);
#pragma unroll
            for (int mt = 0; mt < 4; ++mt) {
                short8 a = *(const short8*)(A +
                    ((long)((kh * 64 + c * 4 + quad) * 64 + mt * 16 + l15) << 3));
                oacc[2 * mt]     = MFMA_(a, b0, oacc[2 * mt]);
                oacc[2 * mt + 1] = MFMA_(a, b1, oacc[2 * mt + 1]);
            }
        }
#pragma unroll
        for (int mt = 0; mt < 4; ++mt)
#pragma unroll
            for (int nt = 0; nt < 2; ++nt)
#pragma unroll
                for (int r = 0; r < 4; ++r) {
                    int row = mt * 16 + quad * 4 + r;
                    pbuf[wv][row][PBI(nt * 16 + l15, row)] = oacc[2 * mt + nt][r];
                }
        __syncthreads();
        for (int i = tid; i < 64 * 128; i += 512) {
            int m = i >> 7, pp2 = i & 127;
            int nh2 = pp2 >> 5, pc = pp2 & 31;
            float v = pbuf[2 * nh2][m][PBI(pc, m)] + pbuf[2 * nh2 + 1][m][PBI(pc, m)]
                    + p.ob[pp2];
            p.out[(long)m * (T_ * P_) + (long)t * P_ + pp2] = sigmoidf_(v);
        }
    }
}

// ---------------------------------------------------------------------------
extern "C" void kernel_launch(void* const* d_in, const int* in_sizes, int n_in,
                              void* d_out, int out_size, void* d_ws, size_t ws_size,
                              hipStream_t stream) {
    const float* z    = (const float*)d_in[0];
    const float* tseq = (const float*)d_in[1];
    const float* fw   = (const float*)d_in[2];
    const float* fb   = (const float*)d_in[3];
    const float* stok = (const float*)d_in[4];
    const float* Wih0 = (const float*)d_in[5];
    const float* Whh0 = (const float*)d_in[6];
    const float* bih0 = (const float*)d_in[7];
    const float* bhh0 = (const float*)d_in[8];
    const float* Wih1 = (const float*)d_in[9];
    const float* Whh1 = (const float*)d_in[10];
    const float* bih1 = (const float*)d_in[11];
    const float* bhh1 = (const float*)d_in[12];
    const float* ow   = (const float*)d_in[13];
    const float* ob   = (const float*)d_in[14];
    float* out = (float*)d_out;

    // Workspace (~94 MB).
    const size_t FULLH = (size_t)(T_ + 1) * BH_ * 2;
    char* ws = (char*)d_ws;
    size_t off = 0;
    __hip_bfloat16* Wih0b = (__hip_bfloat16*)(ws + off); off += (size_t)4 * H_ * P_ * 2;
    __hip_bfloat16* Whh0b = (__hip_bfloat16*)(ws + off); off += (size_t)4 * H_ * H_ * 2;
    __hip_bfloat16* Wih1b = (__hip_bfloat16*)(ws + off); off += (size_t)4 * H_ * H_ * 2;
    __hip_bfloat16* Whh1b = (__hip_bfloat16*)(ws + off); off += (size_t)4 * H_ * H_ * 2;
    __hip_bfloat16* owb   = (__hip_bfloat16*)(ws + off); off += (size_t)P_ * H_ * 2;
    __hip_bfloat16* tseqb = (__hip_bfloat16*)(ws + off); off += (size_t)B_ * T_ * P_ * 2;
    __hip_bfloat16* stokb = (__hip_bfloat16*)(ws + off); off += 256;
    __hip_bfloat16* h1seq = (__hip_bfloat16*)(ws + off); off += FULLH;
    __hip_bfloat16* h2seq = (__hip_bfloat16*)(ws + off); off += FULLH;
    unsigned* cnt         = (unsigned*)(ws + off);       off += (size_t)CNTW * 4;
    unsigned* rdy         = (unsigned*)(ws + off);       off += (size_t)RDYW * 4;

    auto cvt = [&](const float* s, __hip_bfloat16* d, int n) {
        hipLaunchKernelGGL(cvt_f2b, dim3((n / 4 + 255) / 256), dim3(256), 0, stream, s, d, n);
    };
    cvt(Wih0, Wih0b, 4 * H_ * P_);
    cvt(Whh0, Whh0b, 4 * H_ * H_);
    cvt(Wih1, Wih1b, 4 * H_ * H_);
    cvt(Whh1, Whh1b, 4 * H_ * H_);
    cvt(ow,   owb,   P_ * H_);
    cvt(tseq, tseqb, B_ * T_ * P_);
    cvt(stok, stokb, P_);

    // h0 into the t=-1 slots; init cnt/rdy.
    hipLaunchKernelGGL(h0_kernel, dim3(256), dim3(256), 0, stream,
                       z, fw, fb, h1seq, h2seq, cnt, rdy);

    PParams pp;
    pp.tseqb = tseqb; pp.stokb = stokb;
    pp.Wih0b = Wih0b; pp.Whh0b = Whh0b; pp.Wih1b = Wih1b; pp.Whh1b = Whh1b;
    pp.owb = owb;
    pp.bih0 = bih0; pp.bhh0 = bhh0; pp.bih1 = bih1; pp.bhh1 = bhh1; pp.ob = ob;
    pp.h1seq = h1seq; pp.h2seq = h2seq;
    pp.out = out;
    pp.cnt = cnt; pp.rdy = rdy;

    hipFuncSetAttribute((const void*)lstm_persistent,
                        hipFuncAttributeMaxDynamicSharedMemorySize, LDS_TOTAL);
    void* args[] = { &pp };
    hipLaunchCooperativeKernel((void*)lstm_persistent, dim3(256), dim3(512),
                               args, LDS_TOTAL, stream);
}